// Round 3
// baseline (24090.442 us; speedup 1.0000x reference)
//
#include <hip/hip_runtime.h>
#include <math.h>

// ESN forward: x_{t+1} = 0.1*x_t + 0.9*tanh(W_in @ u_t + W @ x_t); y_t = Wout @ x_{t+1}
// W sparse (5%) -> variable-length ELL (round-robin within 8-thread row group).
// 64 cooperative WGs. R7:
//  - single-round-trip exchange: no flags; spin directly on the 8 packed
//    (epoch<<32|fbits) words (one aligned 64B line, written by ONE producer
//    instruction -> all-or-nothing visibility, rare retries). Fence-free.
//  - variable-length gather: rlen[r] from kernel 1; ~13.4 avg int4s vs 21
//    padded. First PF=12 int4s prefetched into VGPRs BEFORE the spin
//    (asm-pinned so the compiler can't sink them past it - R5 lesson).
//  - ONE barrier/step: readout partials -> red[t&1][wave]; tid0 flushes the
//    PREVIOUS step's slot after barrier 1 (which orders write(t)->read(t+1)).
//  - branchless exp2-based tanh on the serial publish path.

#define NX 4096
#define NU 128
#define NY 64
#define TSTEPS 4096
#define CAP 336            // storage pad (mean nnz 204.8, sd 13.9); zero-filled
#define WGS 64
#define TPB 512
#define RPW (NX / WGS)     // 64 rows per workgroup
#define UPT 16             // W_in floats per thread
#define WPT 8              // exchange words / readout floats per thread
#define PF  12             // int4s (=24 entries) prefetched before the spin

typedef unsigned long long u64;
typedef unsigned int u32;

// --- Kernel 1: deterministic dense->ELL compaction + row lengths ---
__global__ void build_ell_kernel(const float* __restrict__ W, int2* __restrict__ ell,
                                 int* __restrict__ rlen) {
    const int r = blockIdx.x;
    const int tid = threadIdx.x;
    const int wv = tid >> 6, ln = tid & 63;
    __shared__ int wave_tot[4];
    __shared__ int base;
    if (tid == 0) base = 0;
    __syncthreads();
    const float* row = W + (size_t)r * NX;
    int2* out = ell + (size_t)r * CAP;
    for (int chunk = 0; chunk < NX; chunk += 256) {
        float w = row[chunk + tid];
        bool p = (w != 0.0f);
        unsigned long long m = __ballot(p);
        int lp = (int)__popcll(m & ((1ull << ln) - 1ull));
        if (ln == 63) wave_tot[wv] = lp + (p ? 1 : 0);
        __syncthreads();
        int wbase = 0;
        #pragma unroll
        for (int i = 0; i < 4; ++i)
            if (i < wv) wbase += wave_tot[i];
        int tot = wave_tot[0] + wave_tot[1] + wave_tot[2] + wave_tot[3];
        if (p) {
            int o = base + wbase + lp;
            if (o < CAP) out[o] = make_int2(chunk + tid, __float_as_int(w));
        }
        __syncthreads();
        if (tid == 0) base += tot;
        __syncthreads();
    }
    // zero-pad remainder: col=0, val=0 contributes exactly 0
    for (int o = base + tid; o < CAP; o += 256) out[o] = make_int2(0, 0);
    if (tid == 0) rlen[r] = (base < CAP) ? base : CAP;
}

// --- Kernel 2: cooperative sequential recurrence, data-is-the-flag ---
__global__ void __launch_bounds__(TPB, 1) esn_kernel(
    const float* __restrict__ UT, const float* __restrict__ x0,
    const float* __restrict__ Win, const float* __restrict__ Wout,
    const int2* __restrict__ ell, const int* __restrict__ rlen,
    u64* __restrict__ xbuf,   // [2][NX] packed (epoch<<32 | float bits)
    float* __restrict__ Y)
{
    __shared__ __align__(16) float xl[2][NX];
    __shared__ float red[2][TPB / 64];

    const int tid = threadIdx.x;
    const int wg  = blockIdx.x;              // 0..63
    const int grp = tid >> 3;                // row group within WG (0..63)
    const int ln  = tid & 7;                 // lane within row group
    const int r   = wg * RPW + grp;          // global row this 8-thread group owns

    // round-robin ELL view: thread ln consumes int4 indices {ln, ln+8, ln+16, ...}
    const int4* ellrow4 = (const int4*)(ell + (size_t)r * CAP) + ln;
    const int   nit     = (rlen[r] + 15) >> 4;   // int4s this group needs

    float4 wreg_in[UPT / 4];                 // Win[r, ln*16 .. +16) pinned
    {
        const float4* winrow = (const float4*)(Win + (size_t)r * NU + ln * UPT);
        #pragma unroll
        for (int i = 0; i < UPT / 4; ++i) wreg_in[i] = winrow[i];
    }
    float wreg_out[WPT];                     // Wout[wg, tid::512] pinned
    {
        const float* woutrow = Wout + (size_t)wg * NX;
        #pragma unroll
        for (int i = 0; i < WPT; ++i) wreg_out[i] = woutrow[tid + i * TPB];
    }

    for (int t = 0; t < TSTEPS; ++t) {
        float* xc = xl[t & 1];

        // ---- x-independent partial: acc = Win[r,:] @ u_t (before spin) ----
        float acc = 0.0f;
        {
            const float4* u4 = (const float4*)(UT + (size_t)t * NU + ln * UPT);
            #pragma unroll
            for (int i = 0; i < UPT / 4; ++i) {
                float4 u = u4[i];
                acc += wreg_in[i].x * u.x + wreg_in[i].y * u.y
                     + wreg_in[i].z * u.z + wreg_in[i].w * u.w;
            }
        }

        // ---- prefetch ELL slice into VGPRs; pin so it can't sink past spin ----
        int4 er[PF];
        #pragma unroll
        for (int j = 0; j < PF; ++j) er[j] = ellrow4[j << 3];
        asm volatile("" :: "v"(er[0].x), "v"(er[1].x), "v"(er[2].x), "v"(er[3].x),
                           "v"(er[4].x), "v"(er[5].x), "v"(er[6].x), "v"(er[7].x),
                           "v"(er[8].x), "v"(er[9].x), "v"(er[10].x), "v"(er[11].x));

        // ---- stage x_t into LDS: spin directly on packed words (one line) ----
        if (t == 0) {
            const float4* xs4 = (const float4*)x0;
            float4* dst = (float4*)(xc + tid * WPT);
            dst[0] = xs4[2 * tid];
            dst[1] = xs4[2 * tid + 1];
        } else {
            const u64* xs = xbuf + (size_t)(t & 1) * NX + (size_t)tid * WPT;
            u64 v[WPT];
            bool ok;
            do {
                ok = true;
                #pragma unroll
                for (int j = 0; j < WPT; ++j)
                    v[j] = __hip_atomic_load(xs + j, __ATOMIC_RELAXED,
                                             __HIP_MEMORY_SCOPE_AGENT);
                #pragma unroll
                for (int j = 0; j < WPT; ++j)
                    ok &= ((u32)(v[j] >> 32) == (u32)t);
            } while (!ok);
            float4 lo = make_float4(__uint_as_float((u32)v[0]), __uint_as_float((u32)v[1]),
                                    __uint_as_float((u32)v[2]), __uint_as_float((u32)v[3]));
            float4 hi = make_float4(__uint_as_float((u32)v[4]), __uint_as_float((u32)v[5]),
                                    __uint_as_float((u32)v[6]), __uint_as_float((u32)v[7]));
            float4* dst = (float4*)(xc + tid * WPT);
            dst[0] = lo;
            dst[1] = hi;
        }
        __syncthreads();   // the ONLY barrier per step

        // ---- deferred Y flush: previous step's wave partials (ordered by barrier) ----
        if (tid == 0 && t >= 2) {
            float s = 0.0f;
            #pragma unroll
            for (int i = 0; i < TPB / 64; ++i) s += red[(t - 1) & 1][i];
            Y[(size_t)(t - 2) * NY + wg] = s;
        }

        // ---- acc += W[r,:] @ x_t: prefetched part + variable-length residue ----
        #pragma unroll
        for (int j = 0; j < PF; ++j) {
            acc += __int_as_float(er[j].y) * xc[er[j].x]
                 + __int_as_float(er[j].w) * xc[er[j].z];
        }
        for (int i = PF; i < nit; ++i) {
            int4 cv = ellrow4[i << 3];
            acc += __int_as_float(cv.y) * xc[cv.x]
                 + __int_as_float(cv.w) * xc[cv.z];
        }
        acc += __shfl_down(acc, 4, 8);
        acc += __shfl_down(acc, 2, 8);
        acc += __shfl_down(acc, 1, 8);

        // ---- publish x_{t+1} immediately (branchless fast tanh) ----
        if (ln == 0) {
            float xold = xc[r];
            float a  = fminf(fmaxf(acc, -10.0f), 10.0f);
            float e  = exp2f(a * 2.885390081777927f);      // e^{2a}
            float th = (e - 1.0f) / (e + 1.0f);            // tanh(a)
            float xnew = __builtin_fmaf(0.9f, th, 0.1f * xold);
            u64 packed = ((u64)(u32)(t + 1) << 32) | (u64)__float_as_uint(xnew);
            __hip_atomic_store(xbuf + (size_t)((t + 1) & 1) * NX + r, packed,
                               __ATOMIC_RELAXED, __HIP_MEMORY_SCOPE_AGENT);
        }

        // ---- readout partials for y_{t-1} (fully off the critical path) ----
        {
            float p = 0.0f;
            #pragma unroll
            for (int i = 0; i < WPT; ++i) p += wreg_out[i] * xc[tid + i * TPB];
            for (int off = 32; off; off >>= 1) p += __shfl_down(p, off, 64);
            if ((tid & 63) == 0) red[t & 1][tid >> 6] = p;
        }
    }

    // ---- final: stage x_T (epoch TSTEPS, buffer 0); flush Y[T-2], Y[T-1] ----
    {
        float* xc = xl[0];
        const u64* xs = xbuf + (size_t)(TSTEPS & 1) * NX + (size_t)tid * WPT;
        u64 v[WPT];
        bool ok;
        do {
            ok = true;
            #pragma unroll
            for (int j = 0; j < WPT; ++j)
                v[j] = __hip_atomic_load(xs + j, __ATOMIC_RELAXED,
                                         __HIP_MEMORY_SCOPE_AGENT);
            #pragma unroll
            for (int j = 0; j < WPT; ++j)
                ok &= ((u32)(v[j] >> 32) == (u32)TSTEPS);
        } while (!ok);
        #pragma unroll
        for (int j = 0; j < WPT; ++j)
            xc[tid * WPT + j] = __uint_as_float((u32)v[j]);
        __syncthreads();

        if (tid == 0) {
            float s = 0.0f;
            #pragma unroll
            for (int i = 0; i < TPB / 64; ++i) s += red[(TSTEPS - 1) & 1][i];
            Y[(size_t)(TSTEPS - 2) * NY + wg] = s;
        }
        float p = 0.0f;
        #pragma unroll
        for (int i = 0; i < WPT; ++i) p += wreg_out[i] * xc[tid + i * TPB];
        for (int off = 32; off; off >>= 1) p += __shfl_down(p, off, 64);
        if ((tid & 63) == 0) red[TSTEPS & 1][tid >> 6] = p;
        __syncthreads();
        if (tid == 0) {
            float s = 0.0f;
            #pragma unroll
            for (int i = 0; i < TPB / 64; ++i) s += red[TSTEPS & 1][i];
            Y[(size_t)(TSTEPS - 1) * NY + wg] = s;
        }
    }
}

extern "C" void kernel_launch(void* const* d_in, const int* in_sizes, int n_in,
                              void* d_out, int out_size, void* d_ws, size_t ws_size,
                              hipStream_t stream) {
    const float* UT   = (const float*)d_in[0];  // [T, NU]
    const float* x0   = (const float*)d_in[1];  // [NX]
    const float* Win  = (const float*)d_in[2];  // [NX, NU]
    const float* W    = (const float*)d_in[3];  // [NX, NX]
    const float* Wout = (const float*)d_in[4];  // [NY, NX]
    float* Y = (float*)d_out;                   // [T*NY]

    char* ws = (char*)d_ws;
    u64*  xbuf = (u64*)ws;                      // 2*NX packed words = 64 KB
    int*  rlen = (int*)(ws + 65536);            // NX ints = 16 KB
    int2* ell  = (int2*)(ws + 81920);           // NX*CAP*8 = 11,010,048 B

    build_ell_kernel<<<dim3(NX), dim3(256), 0, stream>>>(W, ell, rlen);

    void* args[] = { (void*)&UT, (void*)&x0, (void*)&Win, (void*)&Wout,
                     (void*)&ell, (void*)&rlen, (void*)&xbuf, (void*)&Y };
    hipLaunchCooperativeKernel((const void*)esn_kernel, dim3(WGS), dim3(TPB),
                               args, 0, stream);
}

// Round 4
// 21726.317 us; speedup vs baseline: 1.1088x; 1.1088x over previous
//
#include <hip/hip_runtime.h>
#include <math.h>

// ESN forward: x_{t+1} = 0.1*x_t + 0.9*tanh(W_in @ u_t + W @ x_t); y_t = Wout @ x_{t+1}
// 64 cooperative WGs. R8 = R6's proven exchange (hint flag + ONE validated
// epoch-in-data round, fence-free) + ELL table RESIDENT IN LDS.
// Diagnosis: R6's unexplained ~3k cy/step stall == ELL re-streamed from L2
// every step (172 KB/WG / 56 B/cy/CU ~= 3.1k cy) after the barrier. Fix: copy
// each WG's rows into LDS once (CSR, 16-entry-aligned, ~109 KB), gather via
// conflict-free ds_read_b128. Exchange/barriers/readout byte-identical to R6
// (R7 proved direct-polling the data regresses; flags stay).

#define NX 4096
#define NU 128
#define NY 64
#define TSTEPS 4096
#define CAP 336            // global ELL pad (mean nnz 204.8, sd 13.9)
#define WGS 64
#define TPB 512
#define RPW (NX / WGS)     // 64 rows per workgroup
#define UPT 16             // W_in floats per thread
#define WPT 8              // exchange words / readout floats per thread
#define LDSE 15872         // LDS entry capacity (per-WG need ~13.6K +- 0.1K; 20 sigma)

// dynamic LDS layout (bytes)
#define XL_OFF   0                         // float xl[2][NX]  = 32768
#define RED_OFF  32768                     // float red[8]     (pad to 128)
#define META_OFF 32896                     // int offs[64], plens[64] = 512
#define ELL_OFF  33408                     // int2 ell_lds[LDSE] = 126976
#define SMEM_BYTES (ELL_OFF + LDSE * 8)    // 160384 <= 163840

typedef unsigned long long u64;
typedef unsigned int u32;

// --- Kernel 1: deterministic dense->ELL compaction + row lengths + flag zero ---
__global__ void build_ell_kernel(const float* __restrict__ W, int2* __restrict__ ell,
                                 int* __restrict__ rlen, u32* __restrict__ flags) {
    const int r = blockIdx.x;
    const int tid = threadIdx.x;
    if (r == 0 && tid < WGS) flags[tid] = 0;   // must re-zero every launch
    const int wv = tid >> 6, ln = tid & 63;
    __shared__ int wave_tot[4];
    __shared__ int base;
    if (tid == 0) base = 0;
    __syncthreads();
    const float* row = W + (size_t)r * NX;
    int2* out = ell + (size_t)r * CAP;
    for (int chunk = 0; chunk < NX; chunk += 256) {
        float w = row[chunk + tid];
        bool p = (w != 0.0f);
        unsigned long long m = __ballot(p);
        int lp = (int)__popcll(m & ((1ull << ln) - 1ull));
        if (ln == 63) wave_tot[wv] = lp + (p ? 1 : 0);
        __syncthreads();
        int wbase = 0;
        #pragma unroll
        for (int i = 0; i < 4; ++i)
            if (i < wv) wbase += wave_tot[i];
        int tot = wave_tot[0] + wave_tot[1] + wave_tot[2] + wave_tot[3];
        if (p) {
            int o = base + wbase + lp;
            if (o < CAP) out[o] = make_int2(chunk + tid, __float_as_int(w));
        }
        __syncthreads();
        if (tid == 0) base += tot;
        __syncthreads();
    }
    // zero-pad remainder: col=0, val=0 contributes exactly 0
    for (int o = base + tid; o < CAP; o += 256) out[o] = make_int2(0, 0);
    if (tid == 0) rlen[r] = (base < CAP) ? base : CAP;
}

// --- Kernel 2: cooperative sequential recurrence ---
__global__ void __launch_bounds__(TPB, 1) esn_kernel(
    const float* __restrict__ UT, const float* __restrict__ x0,
    const float* __restrict__ Win, const float* __restrict__ Wout,
    const int2* __restrict__ ell, const int* __restrict__ rlen,
    u64* __restrict__ xbuf,   // [2][NX] packed (epoch<<32 | float bits)
    u32* __restrict__ flags,  // [WGS] hint only (data epochs are the gate)
    float* __restrict__ Y)
{
    extern __shared__ __align__(16) char smem[];
    float* xl      = (float*)(smem + XL_OFF);    // [2][NX]
    float* red     = (float*)(smem + RED_OFF);   // [8]
    int*   offs    = (int*)  (smem + META_OFF);  // [64]
    int*   plens   = offs + RPW;                 // [64]
    int2*  ell_lds = (int2*) (smem + ELL_OFF);

    const int tid = threadIdx.x;
    const int wg  = blockIdx.x;              // 0..63
    const int grp = tid >> 3;                // row group within WG (0..63)
    const int ln  = tid & 7;                 // lane within row group
    const int r   = wg * RPW + grp;          // global row this 8-thread group owns
    const int pf  = tid >> 3;                // producer WG of this thread's 8 words

    // ---- prologue: per-row padded lengths + exclusive scan (wave 0) ----
    if (tid < RPW) {
        int rl = rlen[wg * RPW + tid];
        int pl = (rl + 15) & ~15;            // multiple of 16 entries
        int inc = pl;
        #pragma unroll
        for (int d = 1; d < 64; d <<= 1) {
            int o = __shfl_up(inc, d, 64);
            if (tid >= d) inc += o;
        }
        offs[tid]  = inc - pl;               // exclusive, multiple of 16
        plens[tid] = pl;
    }
    __syncthreads();
    const int offg  = offs[grp];
    const int pleng = plens[grp];
    const int trips = pleng >> 4;            // int4s per lane (8 lanes/group)
    const bool use_lds = (offg + pleng) <= LDSE;   // 20-sigma always true

    // ---- copy this group's row into LDS (one-time, ~109 KB/WG) ----
    if (use_lds) {
        const int4* gsrc = (const int4*)(ell + (size_t)r * CAP);
        int4* ldst = (int4*)ell_lds + (offg >> 1);
        for (int i = ln; i < (pleng >> 1); i += 8) ldst[i] = gsrc[i];
    }
    __syncthreads();
    const int4* e4  = (const int4*)ell_lds + (offg >> 1) + ln;   // LDS, round-robin
    const int4* eg4 = (const int4*)(ell + (size_t)r * CAP) + ln; // global fallback

    float4 wreg_in[UPT / 4];                 // Win[r, ln*16 .. +16) pinned
    {
        const float4* winrow = (const float4*)(Win + (size_t)r * NU + ln * UPT);
        #pragma unroll
        for (int i = 0; i < UPT / 4; ++i) wreg_in[i] = winrow[i];
    }
    float wreg_out[WPT];                     // Wout[wg, tid::512] pinned
    {
        const float* woutrow = Wout + (size_t)wg * NX;
        #pragma unroll
        for (int i = 0; i < WPT; ++i) wreg_out[i] = woutrow[tid + i * TPB];
    }

    for (int t = 0; t < TSTEPS; ++t) {
        float* xc = xl + (t & 1) * NX;

        // ---- x-independent partial: acc = Win[r,:] @ u_t (before spin) ----
        float acc = 0.0f;
        {
            const float4* u4 = (const float4*)(UT + (size_t)t * NU + ln * UPT);
            #pragma unroll
            for (int i = 0; i < UPT / 4; ++i) {
                float4 u = u4[i];
                acc += wreg_in[i].x * u.x + wreg_in[i].y * u.y
                     + wreg_in[i].z * u.z + wreg_in[i].w * u.w;
            }
        }

        // ---- stage x_t into LDS (R6 exchange, verbatim) ----
        if (t == 0) {
            const float4* xs4 = (const float4*)x0;
            float4* dst = (float4*)(xc + tid * WPT);
            dst[0] = xs4[2 * tid];
            dst[1] = xs4[2 * tid + 1];
        } else {
            // cheap spin: one 4B relaxed hint (no ordering semantics)
            while (__hip_atomic_load(flags + pf, __ATOMIC_RELAXED,
                                     __HIP_MEMORY_SCOPE_AGENT) < (u32)t) { }
            // validated data round: 8 packed words, one 64B line
            const u64* xs = xbuf + (size_t)(t & 1) * NX + (size_t)tid * WPT;
            u64 v[WPT];
            bool ok;
            do {
                ok = true;
                #pragma unroll
                for (int j = 0; j < WPT; ++j)
                    v[j] = __hip_atomic_load(xs + j, __ATOMIC_RELAXED,
                                             __HIP_MEMORY_SCOPE_AGENT);
                #pragma unroll
                for (int j = 0; j < WPT; ++j)
                    ok &= ((u32)(v[j] >> 32) == (u32)t);
            } while (!ok);
            float4 lo = make_float4(__uint_as_float((u32)v[0]), __uint_as_float((u32)v[1]),
                                    __uint_as_float((u32)v[2]), __uint_as_float((u32)v[3]));
            float4 hi = make_float4(__uint_as_float((u32)v[4]), __uint_as_float((u32)v[5]),
                                    __uint_as_float((u32)v[6]), __uint_as_float((u32)v[7]));
            float4* dst = (float4*)(xc + tid * WPT);
            dst[0] = lo;
            dst[1] = hi;
        }
        __syncthreads();

        // ---- acc += W[r,:] @ x_t (entries from LDS; conflict-free b128) ----
        if (use_lds) {
            #pragma unroll 4
            for (int i = 0; i < trips; ++i) {
                int4 cv = e4[i << 3];
                acc += __int_as_float(cv.y) * xc[cv.x]
                     + __int_as_float(cv.w) * xc[cv.z];
            }
        } else {
            for (int i = 0; i < trips; ++i) {
                int4 cv = eg4[i << 3];
                acc += __int_as_float(cv.y) * xc[cv.x]
                     + __int_as_float(cv.w) * xc[cv.z];
            }
        }
        acc += __shfl_down(acc, 4, 8);
        acc += __shfl_down(acc, 2, 8);
        acc += __shfl_down(acc, 1, 8);

        // ---- publish x_{t+1} immediately: one packed 8B store per row ----
        if (ln == 0) {
            float xnew = 0.1f * xc[r] + 0.9f * tanhf(acc);
            u64 packed = ((u64)(u32)(t + 1) << 32) | (u64)__float_as_uint(xnew);
            __hip_atomic_store(xbuf + (size_t)((t + 1) & 1) * NX + r, packed,
                               __ATOMIC_RELAXED, __HIP_MEMORY_SCOPE_AGENT);
        }

        // ---- readout Y[t-1] = Wout[wg] . x_t; barrier doubles as flag gate ----
        if (t > 0) {
            float a = 0.0f;
            #pragma unroll
            for (int i = 0; i < WPT; ++i) a += wreg_out[i] * xc[tid + i * TPB];
            for (int off = 32; off; off >>= 1) a += __shfl_down(a, off, 64);
            if ((tid & 63) == 0) red[tid >> 6] = a;
        }
        __syncthreads();   // all publishes issued before this point
        if (tid == 0) {
            __hip_atomic_store(flags + wg, (u32)(t + 1),
                               __ATOMIC_RELAXED, __HIP_MEMORY_SCOPE_AGENT);
            if (t > 0) {
                float s = 0.0f;
                #pragma unroll
                for (int i = 0; i < TPB / 64; ++i) s += red[i];
                Y[(size_t)(t - 1) * NY + wg] = s;
            }
        }
    }

    // ---- final: stage x_T (epoch TSTEPS, buffer 0), then Y[T-1] ----
    {
        float* xc = xl;
        while (__hip_atomic_load(flags + pf, __ATOMIC_RELAXED,
                                 __HIP_MEMORY_SCOPE_AGENT) < (u32)TSTEPS) { }
        const u64* xs = xbuf + (size_t)(TSTEPS & 1) * NX + (size_t)tid * WPT;
        u64 v[WPT];
        bool ok;
        do {
            ok = true;
            #pragma unroll
            for (int j = 0; j < WPT; ++j)
                v[j] = __hip_atomic_load(xs + j, __ATOMIC_RELAXED,
                                         __HIP_MEMORY_SCOPE_AGENT);
            #pragma unroll
            for (int j = 0; j < WPT; ++j)
                ok &= ((u32)(v[j] >> 32) == (u32)TSTEPS);
        } while (!ok);
        #pragma unroll
        for (int j = 0; j < WPT; ++j)
            xc[tid * WPT + j] = __uint_as_float((u32)v[j]);
        __syncthreads();

        float a = 0.0f;
        #pragma unroll
        for (int i = 0; i < WPT; ++i) a += wreg_out[i] * xc[tid + i * TPB];
        for (int off = 32; off; off >>= 1) a += __shfl_down(a, off, 64);
        if ((tid & 63) == 0) red[tid >> 6] = a;
        __syncthreads();
        if (tid == 0) {
            float s = 0.0f;
            #pragma unroll
            for (int i = 0; i < TPB / 64; ++i) s += red[i];
            Y[(size_t)(TSTEPS - 1) * NY + wg] = s;
        }
    }
}

extern "C" void kernel_launch(void* const* d_in, const int* in_sizes, int n_in,
                              void* d_out, int out_size, void* d_ws, size_t ws_size,
                              hipStream_t stream) {
    const float* UT   = (const float*)d_in[0];  // [T, NU]
    const float* x0   = (const float*)d_in[1];  // [NX]
    const float* Win  = (const float*)d_in[2];  // [NX, NU]
    const float* W    = (const float*)d_in[3];  // [NX, NX]
    const float* Wout = (const float*)d_in[4];  // [NY, NX]
    float* Y = (float*)d_out;                   // [T*NY]

    char* ws = (char*)d_ws;
    u64*  xbuf  = (u64*)ws;                     // 2*NX packed words = 64 KB
    u32*  flags = (u32*)(ws + 65536);           // 64 hint flags
    int*  rlen  = (int*)(ws + 69632);           // NX ints = 16 KB
    int2* ell   = (int2*)(ws + 86016);          // NX*CAP*8 = 11,010,048 B

    // allow 160 KB dynamic LDS for esn_kernel (host-side attr, not a stream op)
    static bool attr_done = false;
    if (!attr_done) {
        hipFuncSetAttribute((const void*)esn_kernel,
                            hipFuncAttributeMaxDynamicSharedMemorySize, SMEM_BYTES);
        attr_done = true;
    }

    build_ell_kernel<<<dim3(NX), dim3(256), 0, stream>>>(W, ell, rlen, flags);

    void* args[] = { (void*)&UT, (void*)&x0, (void*)&Win, (void*)&Wout,
                     (void*)&ell, (void*)&rlen, (void*)&xbuf, (void*)&flags,
                     (void*)&Y };
    hipLaunchCooperativeKernel((const void*)esn_kernel, dim3(WGS), dim3(TPB),
                               args, SMEM_BYTES, stream);
}